// Round 2
// baseline (707.646 us; speedup 1.0000x reference)
//
#include <hip/hip_runtime.h>
#include <cmath>

// MNEMatch: B pairs of [N,D] fp32; S = x1 @ x2^T per pair; greedy max matching
// (N sequential global-argmax + row/col removal); out[b] = tanh(sum/N).
#define NN 256
#define DD 384
#define BM 128
#define BK 16

// ---------------- Kernel 1: batched S = A @ B^T (fp32) ---------------------
// 128x128 tile, 256 threads, 8x8 micro-tile per thread (two 4-row x two 4-col
// groups -> float4 LDS reads). Per kk: 4 ds_read_b128 + 64 v_fma -> FMA-bound.
__global__ __launch_bounds__(256) void gemm_bt(const float* __restrict__ X1,
                                               const float* __restrict__ X2,
                                               float* __restrict__ S) {
  const int pair  = blockIdx.z;
  const int rbase = blockIdx.y * BM;
  const int cbase = blockIdx.x * BM;
  const float* A  = X1 + (size_t)pair * NN * DD;
  const float* Bm = X2 + (size_t)pair * NN * DD;

  __shared__ float As[BK][BM];   // [k][row] (transposed at stage time)
  __shared__ float Bs[BK][BM];

  const int tid  = threadIdx.x;
  const int tx   = tid & 15;       // col group 0..15
  const int ty   = tid >> 4;       // row group 0..15
  const int srow = tid >> 1;       // staging row 0..127
  const int skq  = (tid & 1) * 8;  // staging k offset 0 or 8

  float acc[2][2][4][4] = {};      // [rowgrp][colgrp][row][col]

  const float* Arow = A  + (size_t)(rbase + srow) * DD + skq;
  const float* Brow = Bm + (size_t)(cbase + srow) * DD + skq;

  for (int k0 = 0; k0 < DD; k0 += BK) {
    float4 a0 = *(const float4*)(Arow + k0);
    float4 a1 = *(const float4*)(Arow + k0 + 4);
    float4 b0 = *(const float4*)(Brow + k0);
    float4 b1 = *(const float4*)(Brow + k0 + 4);
    __syncthreads();
    As[skq+0][srow]=a0.x; As[skq+1][srow]=a0.y; As[skq+2][srow]=a0.z; As[skq+3][srow]=a0.w;
    As[skq+4][srow]=a1.x; As[skq+5][srow]=a1.y; As[skq+6][srow]=a1.z; As[skq+7][srow]=a1.w;
    Bs[skq+0][srow]=b0.x; Bs[skq+1][srow]=b0.y; Bs[skq+2][srow]=b0.z; Bs[skq+3][srow]=b0.w;
    Bs[skq+4][srow]=b1.x; Bs[skq+5][srow]=b1.y; Bs[skq+6][srow]=b1.z; Bs[skq+7][srow]=b1.w;
    __syncthreads();
#pragma unroll
    for (int kk = 0; kk < BK; ++kk) {
      float4 av0 = *(const float4*)&As[kk][ty * 4];
      float4 av1 = *(const float4*)&As[kk][ty * 4 + 64];
      float4 bv0 = *(const float4*)&Bs[kk][tx * 4];
      float4 bv1 = *(const float4*)&Bs[kk][tx * 4 + 64];
      float ar[2][4] = {{av0.x, av0.y, av0.z, av0.w}, {av1.x, av1.y, av1.z, av1.w}};
      float br[2][4] = {{bv0.x, bv0.y, bv0.z, bv0.w}, {bv1.x, bv1.y, bv1.z, bv1.w}};
#pragma unroll
      for (int i = 0; i < 2; ++i)
#pragma unroll
        for (int j = 0; j < 2; ++j)
#pragma unroll
          for (int a = 0; a < 4; ++a)
#pragma unroll
            for (int b = 0; b < 4; ++b)
              acc[i][j][a][b] += ar[i][a] * br[j][b];
    }
  }

  float* Sp = S + (size_t)pair * NN * NN;
#pragma unroll
  for (int i = 0; i < 2; ++i)
#pragma unroll
    for (int a = 0; a < 4; ++a) {
      const int r = rbase + ty * 4 + 64 * i + a;
#pragma unroll
      for (int j = 0; j < 2; ++j) {
        float4 v = make_float4(acc[i][j][a][0], acc[i][j][a][1],
                               acc[i][j][a][2], acc[i][j][a][3]);
        *(float4*)(Sp + (size_t)r * NN + cbase + tx * 4 + 64 * j) = v;
      }
    }
}

// ------------- Kernel 2: greedy matching, ONE WAVE per pair ----------------
// Zero barriers, zero LDS. State in registers:
//   rm[s]/ra[s]: max value / argmax col of row (s*64 + lane); ra = -1 if dead
//   cm[s]: wave-uniform 64-bit alive mask for cols s*64 .. s*64+63
// Per iteration: butterfly argmax over 256 row maxima, broadcast winner,
// register kills, ballot-based dirty detection, whole-wave rescan of rows
// whose cached argmax column just died (expected ~1/iter).
// Tie-break == jnp flat argmax: smallest row, then smallest col, on equals.
__global__ __launch_bounds__(64) void greedy_match(const float* __restrict__ S,
                                                   float* __restrict__ out) {
  const int pair = blockIdx.x;
  const float* Sp = S + (size_t)pair * NN * NN;
  const int lane = threadIdx.x;

  float rm[4];
  int   ra[4];
  unsigned long long cm[4];
#pragma unroll
  for (int i = 0; i < 4; ++i) cm[i] = ~0ull;

  // ---- init: whole-wave argmax of each row, 4 rows in flight for ILP ----
#pragma unroll
  for (int slot = 0; slot < 4; ++slot) {
    for (int rr = 0; rr < 64; rr += 4) {
      float bv[4]; int bc[4];
#pragma unroll
      for (int j = 0; j < 4; ++j) {
        const float* row = Sp + (size_t)(slot * 64 + rr + j) * NN;
        float4 v = *(const float4*)(row + lane * 4);
        float b = v.x; int c = lane * 4;
        if (v.y > b) { b = v.y; c = lane * 4 + 1; }
        if (v.z > b) { b = v.z; c = lane * 4 + 2; }
        if (v.w > b) { b = v.w; c = lane * 4 + 3; }
        bv[j] = b; bc[j] = c;
      }
#pragma unroll
      for (int m = 32; m >= 1; m >>= 1) {
#pragma unroll
        for (int j = 0; j < 4; ++j) {
          float ov = __shfl_xor(bv[j], m, 64);
          int   oc = __shfl_xor(bc[j], m, 64);
          if (ov > bv[j] || (ov == bv[j] && oc < bc[j])) { bv[j] = ov; bc[j] = oc; }
        }
      }
#pragma unroll
      for (int j = 0; j < 4; ++j)
        if (lane == rr + j) { rm[slot] = bv[j]; ra[slot] = bc[j]; }
    }
  }

  float sum = 0.0f;

  for (int it = 0; it < NN; ++it) {
    // --- argmax over the 256 cached row maxima ---
    float bv = -INFINITY; int br = 0;
#pragma unroll
    for (int i = 0; i < 4; ++i) {       // r = i*64+lane ascends with i:
      if (rm[i] > bv) { bv = rm[i]; br = i * 64 + lane; }  // '>' keeps min r in-lane
    }
#pragma unroll
    for (int m = 32; m >= 1; m >>= 1) {
      float ov = __shfl_xor(bv, m, 64);
      int   orr = __shfl_xor(br, m, 64);
      if (ov > bv || (ov == bv && orr < br)) { bv = ov; br = orr; }
    }
    sum += bv;                           // uniform across lanes

    // --- fetch winner's column, kill row + col (all register ops) ---
    const int bslot = br >> 6, blane = br & 63;
    int myra = 0;
#pragma unroll
    for (int i = 0; i < 4; ++i) if (bslot == i) myra = ra[i];
    const int bc = __shfl(myra, blane, 64);
#pragma unroll
    for (int i = 0; i < 4; ++i)
      if (bslot == i && lane == blane) { rm[i] = -INFINITY; ra[i] = -1; }
    const int cslot = bc >> 6;
#pragma unroll
    for (int i = 0; i < 4; ++i)
      if (cslot == i) cm[i] &= ~(1ull << (bc & 63));

    // --- rescan rows whose cached argmax column just died ---
#pragma unroll
    for (int i = 0; i < 4; ++i) {
      unsigned long long m = __ballot(ra[i] == bc);
      while (m) {
        const int l = __builtin_ctzll(m); m &= m - 1;
        const int r = i * 64 + l;
        const float* row = Sp + (size_t)r * NN;
        float b = -INFINITY; int c = 0;
#pragma unroll
        for (int j = 0; j < 4; ++j) {    // cc ascends with j in-lane
          const int cc = j * 64 + lane;
          float v = row[cc];
          v = ((cm[j] >> lane) & 1ull) ? v : -INFINITY;
          if (v > b) { b = v; c = cc; }
        }
#pragma unroll
        for (int mm = 32; mm >= 1; mm >>= 1) {
          float ov = __shfl_xor(b, mm, 64);
          int   oc = __shfl_xor(c, mm, 64);
          if (ov > b || (ov == b && oc < c)) { b = ov; c = oc; }
        }
        if (lane == l) { rm[i] = b; ra[i] = c; }
      }
    }
  }

  if (lane == 0) out[pair] = tanhf(sum / (float)NN);
}

extern "C" void kernel_launch(void* const* d_in, const int* in_sizes, int n_in,
                              void* d_out, int out_size, void* d_ws, size_t ws_size,
                              hipStream_t stream) {
  const float* x1 = (const float*)d_in[0];
  const float* x2 = (const float*)d_in[1];
  float* out = (float*)d_out;
  float* S   = (float*)d_ws;           // needs B*N*N*4 = 32 MiB

  const int B = in_sizes[0] / (NN * DD);

  dim3 ggrid(NN / BM, NN / BM, B);     // 2 x 2 x 128 = 512 blocks
  gemm_bt<<<ggrid, 256, 0, stream>>>(x1, x2, S);
  greedy_match<<<B, 64, 0, stream>>>(S, out);
}

// Round 3
// 548.880 us; speedup vs baseline: 1.2893x; 1.2893x over previous
//
#include <hip/hip_runtime.h>
#include <cmath>

// MNEMatch: B pairs of [N,D] fp32; S = x1 @ x2^T per pair; greedy max matching
// (N sequential global-argmax + row/col removal); out[b] = tanh(sum/N).
#define NN 256
#define DD 384
#define BM 128
#define BK 16

// ---------------- Kernel 1: batched S = A @ B^T (fp32) ---------------------
__global__ __launch_bounds__(256) void gemm_bt(const float* __restrict__ X1,
                                               const float* __restrict__ X2,
                                               float* __restrict__ S) {
  const int pair  = blockIdx.z;
  const int rbase = blockIdx.y * BM;
  const int cbase = blockIdx.x * BM;
  const float* A  = X1 + (size_t)pair * NN * DD;
  const float* Bm = X2 + (size_t)pair * NN * DD;

  __shared__ float As[BK][BM];
  __shared__ float Bs[BK][BM];

  const int tid  = threadIdx.x;
  const int tx   = tid & 15;
  const int ty   = tid >> 4;
  const int srow = tid >> 1;
  const int skq  = (tid & 1) * 8;

  float acc[2][2][4][4] = {};

  const float* Arow = A  + (size_t)(rbase + srow) * DD + skq;
  const float* Brow = Bm + (size_t)(cbase + srow) * DD + skq;

  for (int k0 = 0; k0 < DD; k0 += BK) {
    float4 a0 = *(const float4*)(Arow + k0);
    float4 a1 = *(const float4*)(Arow + k0 + 4);
    float4 b0 = *(const float4*)(Brow + k0);
    float4 b1 = *(const float4*)(Brow + k0 + 4);
    __syncthreads();
    As[skq+0][srow]=a0.x; As[skq+1][srow]=a0.y; As[skq+2][srow]=a0.z; As[skq+3][srow]=a0.w;
    As[skq+4][srow]=a1.x; As[skq+5][srow]=a1.y; As[skq+6][srow]=a1.z; As[skq+7][srow]=a1.w;
    Bs[skq+0][srow]=b0.x; Bs[skq+1][srow]=b0.y; Bs[skq+2][srow]=b0.z; Bs[skq+3][srow]=b0.w;
    Bs[skq+4][srow]=b1.x; Bs[skq+5][srow]=b1.y; Bs[skq+6][srow]=b1.z; Bs[skq+7][srow]=b1.w;
    __syncthreads();
#pragma unroll
    for (int kk = 0; kk < BK; ++kk) {
      float4 av0 = *(const float4*)&As[kk][ty * 4];
      float4 av1 = *(const float4*)&As[kk][ty * 4 + 64];
      float4 bv0 = *(const float4*)&Bs[kk][tx * 4];
      float4 bv1 = *(const float4*)&Bs[kk][tx * 4 + 64];
      float ar[2][4] = {{av0.x, av0.y, av0.z, av0.w}, {av1.x, av1.y, av1.z, av1.w}};
      float br[2][4] = {{bv0.x, bv0.y, bv0.z, bv0.w}, {bv1.x, bv1.y, bv1.z, bv1.w}};
#pragma unroll
      for (int i = 0; i < 2; ++i)
#pragma unroll
        for (int j = 0; j < 2; ++j)
#pragma unroll
          for (int a = 0; a < 4; ++a)
#pragma unroll
            for (int b = 0; b < 4; ++b)
              acc[i][j][a][b] += ar[i][a] * br[j][b];
    }
  }

  float* Sp = S + (size_t)pair * NN * NN;
#pragma unroll
  for (int i = 0; i < 2; ++i)
#pragma unroll
    for (int a = 0; a < 4; ++a) {
      const int r = rbase + ty * 4 + 64 * i + a;
#pragma unroll
      for (int j = 0; j < 2; ++j) {
        float4 v = make_float4(acc[i][j][a][0], acc[i][j][a][1],
                               acc[i][j][a][2], acc[i][j][a][3]);
        *(float4*)(Sp + (size_t)r * NN + cbase + tx * 4 + 64 * j) = v;
      }
    }
}

// ---------------- DPP wave64 argmax: VALU-speed, result in lane 63 ---------
// Tie-break: on equal value, smaller index wins (matches jnp flat argmax).
// row_shr pulls from lower lanes; disabled/unsourced lanes keep 'old' = self.
#define DPP_STEP(ctrl, rmask)                                                  \
  {                                                                            \
    int vi  = __float_as_int(v);                                               \
    int v2b = __builtin_amdgcn_update_dpp(vi, vi, (ctrl), (rmask), 0xf, false);\
    int i2  = __builtin_amdgcn_update_dpp(c,  c,  (ctrl), (rmask), 0xf, false);\
    float v2 = __int_as_float(v2b);                                            \
    if (v2 > v || (v2 == v && i2 < c)) { v = v2; c = i2; }                     \
  }

__device__ __forceinline__ void dpp_argmax(float& v, int& c) {
  DPP_STEP(0x111, 0xf)  // row_shr:1
  DPP_STEP(0x112, 0xf)  // row_shr:2
  DPP_STEP(0x114, 0xf)  // row_shr:4
  DPP_STEP(0x118, 0xf)  // row_shr:8   -> lanes 15/31/47/63 hold row-of-16 max
  DPP_STEP(0x142, 0xa)  // row_bcast:15 -> lane 31 = max(0-31), 63 = max(32-63)
  DPP_STEP(0x143, 0xc)  // row_bcast:31 -> lane 63 = max(0-63)
}

__device__ __forceinline__ float rdlane_f(float v, int l) {
  return __int_as_float(__builtin_amdgcn_readlane(__float_as_int(v), l));
}

// ------------- Kernel 2: greedy matching, ONE WAVE per pair ----------------
// State in registers: rm[s]/ra[s] = max/argmax-col of row s*64+lane (ra=-1
// dead); colnib = 4-bit alive mask for this lane's cols 4*lane..4*lane+3.
__global__ __launch_bounds__(64) void greedy_match(const float* __restrict__ S,
                                                   float* __restrict__ out) {
  const int pair = blockIdx.x;
  const float* Sp = S + (size_t)pair * NN * NN;
  const int lane = threadIdx.x;

  float rm[4];
  int   ra[4];
  int   colnib = 0xF;

  // ---- init: per-row wave argmax from global (coalesced float4), 8 chains --
#pragma unroll
  for (int slot = 0; slot < 4; ++slot) {
    for (int rr = 0; rr < 64; rr += 8) {
      float bv[8]; int bc[8];
#pragma unroll
      for (int j = 0; j < 8; ++j) {
        const float* row = Sp + (size_t)(slot * 64 + rr + j) * NN;
        float4 v = *(const float4*)(row + lane * 4);
        float b = v.x; int c = lane * 4;
        if (v.y > b) { b = v.y; c = lane * 4 + 1; }
        if (v.z > b) { b = v.z; c = lane * 4 + 2; }
        if (v.w > b) { b = v.w; c = lane * 4 + 3; }
        bv[j] = b; bc[j] = c;
      }
#pragma unroll
      for (int j = 0; j < 8; ++j) dpp_argmax(bv[j], bc[j]);
#pragma unroll
      for (int j = 0; j < 8; ++j) {
        float sb = rdlane_f(bv[j], 63);
        int   sc = __builtin_amdgcn_readlane(bc[j], 63);
        if (lane == rr + j) { rm[slot] = sb; ra[slot] = sc; }
      }
    }
  }

  float sum = 0.0f;

  for (int it = 0; it < NN; ++it) {
    // --- argmax over 256 cached row maxima (r = slot*64+lane) ---
    float v = rm[0]; int c = lane;
    if (rm[1] > v) { v = rm[1]; c = 64 + lane; }
    if (rm[2] > v) { v = rm[2]; c = 128 + lane; }
    if (rm[3] > v) { v = rm[3]; c = 192 + lane; }
    dpp_argmax(v, c);
    const int   s_br = __builtin_amdgcn_readlane(c, 63);
    const float s_bv = rdlane_f(v, 63);
    sum += s_bv;

    const int bslot = s_br >> 6, blane = s_br & 63;
    // winner row's cached argmax column
    int myra = ra[0];
    if (bslot == 1) myra = ra[1];
    if (bslot == 2) myra = ra[2];
    if (bslot == 3) myra = ra[3];
    const int bc = __builtin_amdgcn_readlane(myra, blane);

    // kill row
    if (lane == blane) {
      if (bslot == 0) { rm[0] = -INFINITY; ra[0] = -1; }
      if (bslot == 1) { rm[1] = -INFINITY; ra[1] = -1; }
      if (bslot == 2) { rm[2] = -INFINITY; ra[2] = -1; }
      if (bslot == 3) { rm[3] = -INFINITY; ra[3] = -1; }
    }
    // kill col (owner lane's nibble)
    if (lane == (bc >> 2)) colnib &= ~(1 << (bc & 3));

    // --- rescan rows whose cached argmax column just died (~1/iter) ---
#pragma unroll
    for (int i = 0; i < 4; ++i) {
      unsigned long long m = __ballot(ra[i] == bc);
      while (m) {
        const int l = __builtin_ctzll(m); m &= m - 1;
        const float* row = Sp + (size_t)(i * 64 + l) * NN;
        float4 x = *(const float4*)(row + lane * 4);
        float b = -INFINITY; int cc = 0;
        float xv[4] = {x.x, x.y, x.z, x.w};
#pragma unroll
        for (int k = 0; k < 4; ++k) {
          float val = ((colnib >> k) & 1) ? xv[k] : -INFINITY;
          if (val > b) { b = val; cc = lane * 4 + k; }
        }
        dpp_argmax(b, cc);
        const float sb = rdlane_f(b, 63);
        const int   sc = __builtin_amdgcn_readlane(cc, 63);
        if (lane == l) { rm[i] = sb; ra[i] = sc; }
      }
    }
  }

  if (lane == 0) out[pair] = tanhf(sum / (float)NN);
}

extern "C" void kernel_launch(void* const* d_in, const int* in_sizes, int n_in,
                              void* d_out, int out_size, void* d_ws, size_t ws_size,
                              hipStream_t stream) {
  const float* x1 = (const float*)d_in[0];
  const float* x2 = (const float*)d_in[1];
  float* out = (float*)d_out;
  float* S   = (float*)d_ws;           // needs B*N*N*4 = 32 MiB

  const int B = in_sizes[0] / (NN * DD);

  dim3 ggrid(NN / BM, NN / BM, B);
  gemm_bt<<<ggrid, 256, 0, stream>>>(x1, x2, S);
  greedy_match<<<B, 64, 0, stream>>>(S, out);
}